// Round 4
// baseline (256.286 us; speedup 1.0000x reference)
//
#include <hip/hip_runtime.h>
#include <stdint.h>

// B=2, S=2048, H=16, dk=64, D=1024. All-bf16 MFMA pipeline, fp32 accumulate.
// R1: XOR-swizzled LDS (conflicts 2.3e7 -> 2.1e6).
// R2: exp2 softmax (log2e folded into Q scale) + v_cvt_pk_bf16_f32 + ones-MFMA rowsum.
// R3: pass fusion 5->3 kernels: fp32->bf16 conversion inlined into GEMM staging
//     (float4 loads + cvt_pk + ds_write_b128, same LDS layout); V written
//     TRANSPOSED directly by gemm_qkv epilogue (b64 stores along s).
// ws (u16 elems): Qh@0 Kh@4M Vt@8M comb@12M  (32 MB).

typedef float f32x4 __attribute__((ext_vector_type(4)));
typedef __bf16 bf16x8 __attribute__((ext_vector_type(8)));
typedef unsigned short u16;

__device__ __forceinline__ u16 f2bf(float x){
  unsigned u = __float_as_uint(x);
  u += 0x7fffu + ((u>>16)&1u);           // RNE
  return (u16)(u>>16);
}
__device__ __forceinline__ unsigned cvt_pk_bf16(float a, float b){
  unsigned r;
  asm("v_cvt_pk_bf16_f32 %0, %1, %2" : "=v"(r) : "v"(a), "v"(b));
  return r;                               // lo16 = bf16(a), hi16 = bf16(b), RNE
}
__device__ __forceinline__ void glds16(const void* g, void* l){
  __builtin_amdgcn_global_load_lds((__attribute__((address_space(1))) void*)g,
                                   (__attribute__((address_space(3))) void*)l, 16, 0, 0);
}
#define MFMA16(a,b,c) __builtin_amdgcn_mfma_f32_16x16x32_bf16(a,b,c,0,0,0)

// ---------------- 128x128 bf16 NT-GEMM core (m97 structure) ----------------
// C[m,n] = sum_k A[m,k]*W[n,k] + bias[n].
// CA/CB: operand is fp32 in global -> inline convert during staging.
// mode 0: bf16 head-layout out (*scale); 1: fp32 row-major; 2: bf16 V-transposed.
template<bool CA, bool CB>
__device__ __forceinline__ void gemm_core(const void* __restrict__ Aptr,
                                          const void* __restrict__ Bptr,
                                          const float* __restrict__ bias,
                                          int mode, float scale,
                                          u16* __restrict__ outB, float* __restrict__ outF)
{
  __shared__ __align__(16) u16 As[128*32];
  __shared__ __align__(16) u16 Bs[128*32];
  const int tid  = threadIdx.x;
  const int lane = tid & 63, w = tid >> 6;
  const int quad = lane >> 4, l15 = lane & 15;
  const int m0 = blockIdx.y*128, n0 = blockIdx.x*128;
  const int wm = (w>>1)*64, wn = (w&1)*64;
  const int sw = (l15>>1)&3;                 // frag-read XOR key

  f32x4 acc[4][4];
  #pragma unroll
  for (int i=0;i<4;i++)
    #pragma unroll
    for (int j=0;j<4;j++) acc[i][j] = (f32x4){0.f,0.f,0.f,0.f};

  for (int kt = 0; kt < 1024; kt += 32){
    #pragma unroll
    for (int t=0;t<2;t++){
      int id = t*256 + tid;
      int r = id>>2;
      int gc = (id&3) ^ ((id>>3)&3);         // global chunk permuted within 64B/128B row window
      size_t ga = (size_t)(m0+r)*1024 + kt + gc*8;
      size_t gb = (size_t)(n0+r)*1024 + kt + gc*8;
      if (CA){
        const float* g = (const float*)Aptr + ga;
        float4 x0 = *(const float4*)g, x1 = *(const float4*)(g+4);
        uint4 pk; pk.x = cvt_pk_bf16(x0.x,x0.y); pk.y = cvt_pk_bf16(x0.z,x0.w);
                  pk.z = cvt_pk_bf16(x1.x,x1.y); pk.w = cvt_pk_bf16(x1.z,x1.w);
        *(uint4*)&As[id*8] = pk;
      } else {
        glds16((const u16*)Aptr + ga, (void*)&As[id*8]);
      }
      if (CB){
        const float* g = (const float*)Bptr + gb;
        float4 x0 = *(const float4*)g, x1 = *(const float4*)(g+4);
        uint4 pk; pk.x = cvt_pk_bf16(x0.x,x0.y); pk.y = cvt_pk_bf16(x0.z,x0.w);
                  pk.z = cvt_pk_bf16(x1.x,x1.y); pk.w = cvt_pk_bf16(x1.z,x1.w);
        *(uint4*)&Bs[id*8] = pk;
      } else {
        glds16((const u16*)Bptr + gb, (void*)&Bs[id*8]);
      }
    }
    __syncthreads();
    bf16x8 af[4], bfv[4];
    #pragma unroll
    for (int i=0;i<4;i++) af[i]  = *(const bf16x8*)&As[(wm + i*16 + l15)*32 + (quad^sw)*8];
    #pragma unroll
    for (int j=0;j<4;j++) bfv[j] = *(const bf16x8*)&Bs[(wn + j*16 + l15)*32 + (quad^sw)*8];
    #pragma unroll
    for (int i=0;i<4;i++)
      #pragma unroll
      for (int j=0;j<4;j++)
        acc[i][j] = MFMA16(af[i], bfv[j], acc[i][j]);
    __syncthreads();
  }

  if (mode == 2){
    // V: write transposed head layout Vt[bh][d][s]; 4 consecutive C/D rows
    // (= consecutive s, fixed d=col) pack into one 8B store.
    #pragma unroll
    for (int i=0;i<4;i++)
      #pragma unroll
      for (int j=0;j<4;j++){
        int row = m0 + wm + i*16 + quad*4;         // s base (4 consecutive)
        int col = n0 + wn + j*16 + l15;            // n = h*64+d
        float bc = bias[col];
        uint2 pk;
        pk.x = cvt_pk_bf16(acc[i][j][0]+bc, acc[i][j][1]+bc);
        pk.y = cvt_pk_bf16(acc[i][j][2]+bc, acc[i][j][3]+bc);
        int bh = ((row>>11)<<4) + (col>>6);
        size_t o = ((size_t)bh*64 + (col&63))*2048 + (row&2047);
        *(uint2*)(outB + o) = pk;
      }
  } else {
    #pragma unroll
    for (int i=0;i<4;i++)
      #pragma unroll
      for (int j=0;j<4;j++)
        #pragma unroll
        for (int r=0;r<4;r++){
          int row = m0 + wm + i*16 + quad*4 + r;   // m (= b*2048+s)
          int col = n0 + wn + j*16 + l15;          // n (= h*64+d)
          float vv = (acc[i][j][r] + bias[col]) * scale;
          if (mode==0){
            size_t o = ((size_t)((row>>11)*16 + (col>>6))*2048 + (row&2047))*64 + (col&63);
            outB[o] = f2bf(vv);
          } else {
            outF[(size_t)row*1024 + col] = vv;
          }
        }
  }
}

__global__ __launch_bounds__(256,3) void gemm_qkv(
  const float* __restrict__ q, const float* __restrict__ k, const float* __restrict__ v,
  const float* __restrict__ wq, const float* __restrict__ wk, const float* __restrict__ wv,
  const float* __restrict__ bq, const float* __restrict__ bk, const float* __restrict__ bv,
  u16* __restrict__ Qh, u16* __restrict__ Kh, u16* __restrict__ Vt)
{
  const int z = blockIdx.z;
  const float* A  = (z==0)?q:(z==1)?k:v;
  const float* W  = (z==0)?wq:(z==1)?wk:wv;
  const float* bi = (z==0)?bq:(z==1)?bk:bv;
  u16*         O  = (z==0)?Qh:(z==1)?Kh:Vt;
  // Q folds 1/sqrt(dk) * log2(e) so attention uses bare v_exp_f32 (2^x)
  gemm_core<true,true>(A, W, bi, (z==2)?2:0, (z==0)?0.1803368801111243f:1.0f, O, nullptr);
}

__global__ __launch_bounds__(256,3) void gemm_out(
  const u16* __restrict__ comb, const float* __restrict__ Wo,
  const float* __restrict__ bo, float* __restrict__ out)
{
  gemm_core<false,true>(comb, Wo, bo, 1, 1.0f, nullptr, out);
}

// ---------------- flash attention (no-max softmax, exp2 logits) ----------------
// Per block: 128 queries of one (b,h). Computes S^T = K*Q^T so exp(P) C/D regs
// hold 4 consecutive kv rows -> b64 writes into XOR-swizzled P_s; P is wave-local
// (each wave owns its 32 q rows) so no barrier between QK^T and PV.
// Row-sum l = P @ ones via MFMA: same C/D layout as O -> no shuffle reduction.
__global__ __launch_bounds__(256,2) void attn(
  const u16* __restrict__ Q, const u16* __restrict__ K, const u16* __restrict__ Vt,
  u16* __restrict__ comb)
{
  __shared__ __align__(16) u16 K_s[128*64];   // 16 KB  rows=kv(128), 8 chunks, sw = row&7
  __shared__ __align__(16) u16 V_s[64*128];   // 16 KB  rows=d(64), 16 chunks, sw = row&15
  __shared__ __align__(16) u16 P_s[128*128];  // 32 KB  (also Q staging) -> 64 KB total
  const int tid = threadIdx.x;
  const int lane = tid&63, w = tid>>6, quad = lane>>4, l15 = lane&15;
  const int l7 = l15&7;
  const int bh = blockIdx.y, q0 = blockIdx.x*128;
  const u16* Qb = Q  + ((size_t)bh*2048 + q0)*64;
  const u16* Kb = K  + (size_t)bh*2048*64;
  const u16* Vb = Vt + (size_t)bh*64*2048;

  // stage Q tile into P_s: rows of 64 elems, chunk ^ (row&7)
  #pragma unroll
  for (int it=0; it<4; it++){
    int id = it*256 + tid;
    int gc = (id&7) ^ ((id>>3)&7);
    glds16(Qb + (size_t)(id>>3)*64 + gc*8, (void*)&P_s[id*8]);
  }
  __syncthreads();
  bf16x8 qa[2][2];                             // B-operand frags: q = w*32+c2*16+l15
  #pragma unroll
  for (int c2=0; c2<2; c2++)
    #pragma unroll
    for (int ks=0; ks<2; ks++)
      qa[c2][ks] = *(const bf16x8*)&P_s[(w*32 + c2*16 + l15)*64 + ((ks*4+quad)^l7)*8];
  __syncthreads();                             // all waves done with Q before P_s reuse

  const __bf16 one1 = (__bf16)1.0f;
  const bf16x8 ones = (bf16x8){one1,one1,one1,one1,one1,one1,one1,one1};

  f32x4 O[2][4];
  #pragma unroll
  for (int rt=0; rt<2; rt++)
    #pragma unroll
    for (int dt=0; dt<4; dt++) O[rt][dt] = (f32x4){0.f,0.f,0.f,0.f};
  f32x4 lacc[2] = {(f32x4){0.f,0.f,0.f,0.f}, (f32x4){0.f,0.f,0.f,0.f}};

  for (int t=0; t<16; t++){
    const int kv0 = t*128;
    #pragma unroll
    for (int it=0; it<4; it++){
      int id = it*256 + tid;
      int gck = (id&7)  ^ ((id>>3)&7);    // K: 8 chunks/row of 64 elems
      int gcv = (id&15) ^ ((id>>4)&15);   // V: 16 chunks/row of 128 elems
      glds16(Kb + (size_t)(kv0 + (id>>3))*64 + gck*8, (void*)&K_s[id*8]);
      glds16(Vb + (size_t)(id>>4)*2048 + kv0 + gcv*8, (void*)&V_s[id*8]);
    }
    __syncthreads();

    // S^T tiles: A = K (m=kv), B = Q (n=q); 2^s -> swizzled P_s
    #pragma unroll
    for (int r8=0; r8<8; r8++){
      bf16x8 ka0 = *(const bf16x8*)&K_s[(r8*16 + l15)*64 + ((0+quad)^l7)*8];
      bf16x8 ka1 = *(const bf16x8*)&K_s[(r8*16 + l15)*64 + ((4+quad)^l7)*8];
      #pragma unroll
      for (int c2=0; c2<2; c2++){
        f32x4 s = (f32x4){0.f,0.f,0.f,0.f};
        s = MFMA16(ka0, qa[c2][0], s);
        s = MFMA16(ka1, qa[c2][1], s);
        // lane holds S^T[kv=r8*16+quad*4+i][q=w*32+c2*16+l15]
        int qq   = w*32 + c2*16 + l15;
        int chnk = (r8*2 + (quad>>1)) ^ l15;       // (kv>>3) ^ (q&15)
        int off  = qq*128 + chnk*8 + (quad&1)*4;
        uint2 pw;
        pw.x = cvt_pk_bf16(__builtin_amdgcn_exp2f(s[0]), __builtin_amdgcn_exp2f(s[1]));
        pw.y = cvt_pk_bf16(__builtin_amdgcn_exp2f(s[2]), __builtin_amdgcn_exp2f(s[3]));
        *(uint2*)&P_s[off] = pw;                   // b64, 4 consecutive kv
      }
    }

    // PV: O[q][d] += P[q][kv] * Vt[d][kv];  l[q] += P[q][kv] * 1
    bf16x8 pa[2][4];
    #pragma unroll
    for (int rt=0; rt<2; rt++)
      #pragma unroll
      for (int kk=0; kk<4; kk++){
        int qq   = w*32 + rt*16 + l15;
        int chnk = (kk*4 + quad) ^ l15;
        pa[rt][kk] = *(const bf16x8*)&P_s[qq*128 + chnk*8];
      }
    #pragma unroll
    for (int kk=0; kk<4; kk++){
      lacc[0] = MFMA16(pa[0][kk], ones, lacc[0]);
      lacc[1] = MFMA16(pa[1][kk], ones, lacc[1]);
    }
    #pragma unroll
    for (int dt=0; dt<4; dt++)
      #pragma unroll
      for (int kk=0; kk<4; kk++){
        bf16x8 vb = *(const bf16x8*)&V_s[(dt*16 + l15)*128 + (((kk*4+quad)^l15))*8];
        O[0][dt] = MFMA16(pa[0][kk], vb, O[0][dt]);
        O[1][dt] = MFMA16(pa[1][kk], vb, O[1][dt]);
      }
    __syncthreads();   // before next K/V staging
  }

  // normalize: lacc has the same C/D layout as O -> direct per-reg divide
  const int b = bh>>4, h = bh&15;
  #pragma unroll
  for (int rt=0; rt<2; rt++)
    #pragma unroll
    for (int i=0;i<4;i++){
      float inv = 1.0f/lacc[rt][i];
      int qrow  = q0 + w*32 + rt*16 + quad*4 + i;
      #pragma unroll
      for (int dt=0; dt<4; dt++){
        size_t o = ((size_t)b*2048 + qrow)*1024 + (size_t)h*64 + dt*16 + l15;
        comb[o] = f2bf(O[rt][dt][i] * inv);
      }
    }
}

extern "C" void kernel_launch(void* const* d_in, const int* in_sizes, int n_in,
                              void* d_out, int out_size, void* d_ws, size_t ws_size,
                              hipStream_t stream)
{
  const float* q  = (const float*)d_in[0];
  const float* k  = (const float*)d_in[1];
  const float* v  = (const float*)d_in[2];
  const float* Wq = (const float*)d_in[3];
  const float* bq = (const float*)d_in[4];
  const float* Wk = (const float*)d_in[5];
  const float* bk = (const float*)d_in[6];
  const float* Wv = (const float*)d_in[7];
  const float* bv = (const float*)d_in[8];
  const float* Wo = (const float*)d_in[9];
  const float* bo = (const float*)d_in[10];
  float* out = (float*)d_out;

  u16* ws   = (u16*)d_ws;
  u16* Qh   = ws;
  u16* Kh   = ws + ((size_t)4u<<20);
  u16* Vt   = ws + ((size_t)8u<<20);
  u16* comb = ws + ((size_t)12u<<20);

  gemm_qkv<<<dim3(8,32,3), 256, 0, stream>>>(q, k, v, Wq, Wk, Wv, bq, bk, bv, Qh, Kh, Vt);
  attn<<<dim3(16,32), 256, 0, stream>>>(Qh, Kh, Vt, comb);
  gemm_out<<<dim3(8,32), 256, 0, stream>>>(comb, Wo, bo, out);
}

// Round 5
// 223.012 us; speedup vs baseline: 1.1492x; 1.1492x over previous
//
#include <hip/hip_runtime.h>
#include <stdint.h>

// B=2, S=2048, H=16, dk=64, D=1024. All-bf16 MFMA pipeline, fp32 accumulate.
// R1: XOR-swizzled LDS (conflicts 2.3e7 -> 2.1e6).
// R2: exp2 softmax (log2e folded into Q scale) + v_cvt_pk_bf16_f32 + ones-MFMA rowsum.
// R4: REVERTED inline-cvt staging (latency-bound: MfmaUtil 12%, VALU 10%) ->
//     back to cvt_all + glds16. KEPT V-transposed gemm_qkv epilogue (transpose_v
//     kernel deleted). gemm_out retiled 128x128 -> 64x128 (1 -> 2 blocks/CU).
// ws (u16): Xq@0 Xk@4M Xv@8M Wq@12M Wk@13M Wv@14M Wo@15M Qh@16M Kh@20M Vt@24M
//           comb reuses Xq (dead after gemm_qkv). Total 28M elems = 56 MB.

typedef float f32x4 __attribute__((ext_vector_type(4)));
typedef __bf16 bf16x8 __attribute__((ext_vector_type(8)));
typedef unsigned short u16;

__device__ __forceinline__ u16 f2bf(float x){
  unsigned u = __float_as_uint(x);
  u += 0x7fffu + ((u>>16)&1u);           // RNE
  return (u16)(u>>16);
}
__device__ __forceinline__ unsigned cvt_pk_bf16(float a, float b){
  unsigned r;
  asm("v_cvt_pk_bf16_f32 %0, %1, %2" : "=v"(r) : "v"(a), "v"(b));
  return r;                               // lo16 = bf16(a), hi16 = bf16(b), RNE
}
__device__ __forceinline__ void glds16(const void* g, void* l){
  __builtin_amdgcn_global_load_lds((__attribute__((address_space(1))) void*)g,
                                   (__attribute__((address_space(3))) void*)l, 16, 0, 0);
}
#define MFMA16(a,b,c) __builtin_amdgcn_mfma_f32_16x16x32_bf16(a,b,c,0,0,0)

// ---------------- fp32 -> bf16 conversion of all 7 tensors ----------------
__global__ __launch_bounds__(256) void cvt_all(
    const float* __restrict__ q, const float* __restrict__ k, const float* __restrict__ v,
    const float* __restrict__ wq, const float* __restrict__ wk, const float* __restrict__ wv,
    const float* __restrict__ wo, u16* __restrict__ ws)
{
  size_t g = ((size_t)blockIdx.x*256 + threadIdx.x)*4;   // elem idx < 16M
  int seg = (int)(g >> 20);                              // 1M-elem segments
  const float* src; size_t base;
  if      (seg <  4){ src=q;  base=(size_t)0u;       }
  else if (seg <  8){ src=k;  base=(size_t)4u<<20;   }
  else if (seg < 12){ src=v;  base=(size_t)8u<<20;   }
  else if (seg ==12){ src=wq; base=(size_t)12u<<20;  }
  else if (seg ==13){ src=wk; base=(size_t)13u<<20;  }
  else if (seg ==14){ src=wv; base=(size_t)14u<<20;  }
  else              { src=wo; base=(size_t)15u<<20;  }
  float4 val = *(const float4*)(src + (g - base));
  uint2 o; o.x = cvt_pk_bf16(val.x, val.y); o.y = cvt_pk_bf16(val.z, val.w);
  *(uint2*)(ws + g) = o;
}

// ---------------- 128x128 bf16 NT-GEMM core (m97 structure, glds16) ----------------
// C[m,n] = sum_k A[m,k]*Wt[n,k] + bias[n].
// MODE 0: bf16 head-layout out (*scale); MODE 2: bf16 V-transposed out.
template<int MODE>
__device__ __forceinline__ void gemm128_core(const u16* __restrict__ A, const u16* __restrict__ Wt,
                                             const float* __restrict__ bias, u16* __restrict__ outB,
                                             float scale)
{
  __shared__ __align__(16) u16 As[128*32];
  __shared__ __align__(16) u16 Bs[128*32];
  const int tid  = threadIdx.x;
  const int lane = tid & 63, w = tid >> 6;
  const int quad = lane >> 4, l15 = lane & 15;
  const int m0 = blockIdx.y*128, n0 = blockIdx.x*128;
  const int wm = (w>>1)*64, wn = (w&1)*64;
  const int sw = (l15>>1)&3;                 // frag-read XOR key

  f32x4 acc[4][4];
  #pragma unroll
  for (int i=0;i<4;i++)
    #pragma unroll
    for (int j=0;j<4;j++) acc[i][j] = (f32x4){0.f,0.f,0.f,0.f};

  for (int kt = 0; kt < 1024; kt += 32){
    #pragma unroll
    for (int t=0;t<2;t++){
      int id = t*256 + tid;
      int r = id>>2;
      int gc = (id&3) ^ ((id>>3)&3);         // global chunk permuted within 64B row window
      glds16(A  + (size_t)(m0+r)*1024 + kt + gc*8, (void*)&As[id*8]);
      glds16(Wt + (size_t)(n0+r)*1024 + kt + gc*8, (void*)&Bs[id*8]);
    }
    __syncthreads();
    bf16x8 af[4], bfv[4];
    #pragma unroll
    for (int i=0;i<4;i++) af[i]  = *(const bf16x8*)&As[(wm + i*16 + l15)*32 + (quad^sw)*8];
    #pragma unroll
    for (int j=0;j<4;j++) bfv[j] = *(const bf16x8*)&Bs[(wn + j*16 + l15)*32 + (quad^sw)*8];
    #pragma unroll
    for (int i=0;i<4;i++)
      #pragma unroll
      for (int j=0;j<4;j++)
        acc[i][j] = MFMA16(af[i], bfv[j], acc[i][j]);
    __syncthreads();
  }

  if (MODE == 2){
    // V: write transposed head layout Vt[bh][d][s]; 4 consecutive C/D rows
    // (= consecutive s, fixed d=col) pack into one 8B store.
    #pragma unroll
    for (int i=0;i<4;i++)
      #pragma unroll
      for (int j=0;j<4;j++){
        int row = m0 + wm + i*16 + quad*4;         // s base (4 consecutive)
        int col = n0 + wn + j*16 + l15;            // n = h*64+d
        float bc = bias[col];
        uint2 pk;
        pk.x = cvt_pk_bf16(acc[i][j][0]+bc, acc[i][j][1]+bc);
        pk.y = cvt_pk_bf16(acc[i][j][2]+bc, acc[i][j][3]+bc);
        int bh = ((row>>11)<<4) + (col>>6);
        size_t o = ((size_t)bh*64 + (col&63))*2048 + (row&2047);
        *(uint2*)(outB + o) = pk;
      }
  } else {
    #pragma unroll
    for (int i=0;i<4;i++)
      #pragma unroll
      for (int j=0;j<4;j++)
        #pragma unroll
        for (int r=0;r<4;r++){
          int row = m0 + wm + i*16 + quad*4 + r;   // m (= b*2048+s)
          int col = n0 + wn + j*16 + l15;          // n (= h*64+d)
          float vv = (acc[i][j][r] + bias[col]) * scale;
          size_t o = ((size_t)((row>>11)*16 + (col>>6))*2048 + (row&2047))*64 + (col&63);
          outB[o] = f2bf(vv);
        }
  }
}

__global__ __launch_bounds__(256,3) void gemm_qkv(
  const u16* __restrict__ Xq, const u16* __restrict__ Xk, const u16* __restrict__ Xv,
  const u16* __restrict__ Wq, const u16* __restrict__ Wk, const u16* __restrict__ Wv,
  const float* __restrict__ bq, const float* __restrict__ bk, const float* __restrict__ bv,
  u16* __restrict__ Qh, u16* __restrict__ Kh, u16* __restrict__ Vt)
{
  const int z = blockIdx.z;
  if (z == 2){
    gemm128_core<2>(Xv, Wv, bv, Vt, 1.0f);
  } else if (z == 1){
    gemm128_core<0>(Xk, Wk, bk, Kh, 1.0f);
  } else {
    // Q folds 1/sqrt(dk) * log2(e) so attention uses bare v_exp_f32 (2^x)
    gemm128_core<0>(Xq, Wq, bq, Qh, 0.1803368801111243f);
  }
}

// ---------------- gemm_out: 64x128 tile (2 blocks/CU), fp32 out ----------------
__global__ __launch_bounds__(256,2) void gemm_out(
  const u16* __restrict__ comb, const u16* __restrict__ Wo,
  const float* __restrict__ bo, float* __restrict__ out)
{
  __shared__ __align__(16) u16 As[64*32];    // 4 KB
  __shared__ __align__(16) u16 Bs[128*32];   // 8 KB
  const int tid  = threadIdx.x;
  const int lane = tid & 63, w = tid >> 6;
  const int quad = lane >> 4, l15 = lane & 15;
  const int m0 = blockIdx.y*64, n0 = blockIdx.x*128;
  const int sw = (l15>>1)&3;

  f32x4 acc[4][2];
  #pragma unroll
  for (int i=0;i<4;i++)
    #pragma unroll
    for (int j=0;j<2;j++) acc[i][j] = (f32x4){0.f,0.f,0.f,0.f};

  for (int kt = 0; kt < 1024; kt += 32){
    {
      int id = tid;                          // 64 rows x 4 chunks = 256
      int r = id>>2;
      int gc = (id&3) ^ ((id>>3)&3);
      glds16(comb + (size_t)(m0+r)*1024 + kt + gc*8, (void*)&As[id*8]);
    }
    #pragma unroll
    for (int t=0;t<2;t++){
      int id = t*256 + tid;
      int r = id>>2;
      int gc = (id&3) ^ ((id>>3)&3);
      glds16(Wo + (size_t)(n0+r)*1024 + kt + gc*8, (void*)&Bs[id*8]);
    }
    __syncthreads();
    bf16x8 af[4], bfv[2];
    #pragma unroll
    for (int i=0;i<4;i++) af[i]  = *(const bf16x8*)&As[(i*16 + l15)*32 + (quad^sw)*8];
    #pragma unroll
    for (int j=0;j<2;j++) bfv[j] = *(const bf16x8*)&Bs[(w*32 + j*16 + l15)*32 + (quad^sw)*8];
    #pragma unroll
    for (int i=0;i<4;i++)
      #pragma unroll
      for (int j=0;j<2;j++)
        acc[i][j] = MFMA16(af[i], bfv[j], acc[i][j]);
    __syncthreads();
  }

  #pragma unroll
  for (int i=0;i<4;i++)
    #pragma unroll
    for (int j=0;j<2;j++)
      #pragma unroll
      for (int r=0;r<4;r++){
        int row = m0 + i*16 + quad*4 + r;
        int col = n0 + w*32 + j*16 + l15;
        out[(size_t)row*1024 + col] = acc[i][j][r] + bo[col];
      }
}

// ---------------- flash attention (no-max softmax, exp2 logits) ----------------
// Per block: 128 queries of one (b,h). Computes S^T = K*Q^T so exp(P) C/D regs
// hold 4 consecutive kv rows -> b64 writes into XOR-swizzled P_s; P is wave-local
// (each wave owns its 32 q rows) so no barrier between QK^T and PV.
// Row-sum l = P @ ones via MFMA: same C/D layout as O -> no shuffle reduction.
__global__ __launch_bounds__(256,2) void attn(
  const u16* __restrict__ Q, const u16* __restrict__ K, const u16* __restrict__ Vt,
  u16* __restrict__ comb)
{
  __shared__ __align__(16) u16 K_s[128*64];   // 16 KB  rows=kv(128), 8 chunks, sw = row&7
  __shared__ __align__(16) u16 V_s[64*128];   // 16 KB  rows=d(64), 16 chunks, sw = row&15
  __shared__ __align__(16) u16 P_s[128*128];  // 32 KB  (also Q staging) -> 64 KB total
  const int tid = threadIdx.x;
  const int lane = tid&63, w = tid>>6, quad = lane>>4, l15 = lane&15;
  const int l7 = l15&7;
  const int bh = blockIdx.y, q0 = blockIdx.x*128;
  const u16* Qb = Q  + ((size_t)bh*2048 + q0)*64;
  const u16* Kb = K  + (size_t)bh*2048*64;
  const u16* Vb = Vt + (size_t)bh*64*2048;

  // stage Q tile into P_s: rows of 64 elems, chunk ^ (row&7)
  #pragma unroll
  for (int it=0; it<4; it++){
    int id = it*256 + tid;
    int gc = (id&7) ^ ((id>>3)&7);
    glds16(Qb + (size_t)(id>>3)*64 + gc*8, (void*)&P_s[id*8]);
  }
  __syncthreads();
  bf16x8 qa[2][2];                             // B-operand frags: q = w*32+c2*16+l15
  #pragma unroll
  for (int c2=0; c2<2; c2++)
    #pragma unroll
    for (int ks=0; ks<2; ks++)
      qa[c2][ks] = *(const bf16x8*)&P_s[(w*32 + c2*16 + l15)*64 + ((ks*4+quad)^l7)*8];
  __syncthreads();                             // all waves done with Q before P_s reuse

  const __bf16 one1 = (__bf16)1.0f;
  const bf16x8 ones = (bf16x8){one1,one1,one1,one1,one1,one1,one1,one1};

  f32x4 O[2][4];
  #pragma unroll
  for (int rt=0; rt<2; rt++)
    #pragma unroll
    for (int dt=0; dt<4; dt++) O[rt][dt] = (f32x4){0.f,0.f,0.f,0.f};
  f32x4 lacc[2] = {(f32x4){0.f,0.f,0.f,0.f}, (f32x4){0.f,0.f,0.f,0.f}};

  for (int t=0; t<16; t++){
    const int kv0 = t*128;
    #pragma unroll
    for (int it=0; it<4; it++){
      int id = it*256 + tid;
      int gck = (id&7)  ^ ((id>>3)&7);    // K: 8 chunks/row of 64 elems
      int gcv = (id&15) ^ ((id>>4)&15);   // V: 16 chunks/row of 128 elems
      glds16(Kb + (size_t)(kv0 + (id>>3))*64 + gck*8, (void*)&K_s[id*8]);
      glds16(Vb + (size_t)(id>>4)*2048 + kv0 + gcv*8, (void*)&V_s[id*8]);
    }
    __syncthreads();

    // S^T tiles: A = K (m=kv), B = Q (n=q); 2^s -> swizzled P_s
    #pragma unroll
    for (int r8=0; r8<8; r8++){
      bf16x8 ka0 = *(const bf16x8*)&K_s[(r8*16 + l15)*64 + ((0+quad)^l7)*8];
      bf16x8 ka1 = *(const bf16x8*)&K_s[(r8*16 + l15)*64 + ((4+quad)^l7)*8];
      #pragma unroll
      for (int c2=0; c2<2; c2++){
        f32x4 s = (f32x4){0.f,0.f,0.f,0.f};
        s = MFMA16(ka0, qa[c2][0], s);
        s = MFMA16(ka1, qa[c2][1], s);
        // lane holds S^T[kv=r8*16+quad*4+i][q=w*32+c2*16+l15]
        int qq   = w*32 + c2*16 + l15;
        int chnk = (r8*2 + (quad>>1)) ^ l15;       // (kv>>3) ^ (q&15)
        int off  = qq*128 + chnk*8 + (quad&1)*4;
        uint2 pw;
        pw.x = cvt_pk_bf16(__builtin_amdgcn_exp2f(s[0]), __builtin_amdgcn_exp2f(s[1]));
        pw.y = cvt_pk_bf16(__builtin_amdgcn_exp2f(s[2]), __builtin_amdgcn_exp2f(s[3]));
        *(uint2*)&P_s[off] = pw;                   // b64, 4 consecutive kv
      }
    }

    // PV: O[q][d] += P[q][kv] * Vt[d][kv];  l[q] += P[q][kv] * 1
    bf16x8 pa[2][4];
    #pragma unroll
    for (int rt=0; rt<2; rt++)
      #pragma unroll
      for (int kk=0; kk<4; kk++){
        int qq   = w*32 + rt*16 + l15;
        int chnk = (kk*4 + quad) ^ l15;
        pa[rt][kk] = *(const bf16x8*)&P_s[qq*128 + chnk*8];
      }
    #pragma unroll
    for (int kk=0; kk<4; kk++){
      lacc[0] = MFMA16(pa[0][kk], ones, lacc[0]);
      lacc[1] = MFMA16(pa[1][kk], ones, lacc[1]);
    }
    #pragma unroll
    for (int dt=0; dt<4; dt++)
      #pragma unroll
      for (int kk=0; kk<4; kk++){
        bf16x8 vb = *(const bf16x8*)&V_s[(dt*16 + l15)*128 + (((kk*4+quad)^l15))*8];
        O[0][dt] = MFMA16(pa[0][kk], vb, O[0][dt]);
        O[1][dt] = MFMA16(pa[1][kk], vb, O[1][dt]);
      }
    __syncthreads();   // before next K/V staging
  }

  // normalize: lacc has the same C/D layout as O -> direct per-reg divide
  const int b = bh>>4, h = bh&15;
  #pragma unroll
  for (int rt=0; rt<2; rt++)
    #pragma unroll
    for (int i=0;i<4;i++){
      float inv = 1.0f/lacc[rt][i];
      int qrow  = q0 + w*32 + rt*16 + quad*4 + i;
      #pragma unroll
      for (int dt=0; dt<4; dt++){
        size_t o = ((size_t)b*2048 + qrow)*1024 + (size_t)h*64 + dt*16 + l15;
        comb[o] = f2bf(O[rt][dt][i] * inv);
      }
    }
}

extern "C" void kernel_launch(void* const* d_in, const int* in_sizes, int n_in,
                              void* d_out, int out_size, void* d_ws, size_t ws_size,
                              hipStream_t stream)
{
  const float* q  = (const float*)d_in[0];
  const float* k  = (const float*)d_in[1];
  const float* v  = (const float*)d_in[2];
  const float* Wq = (const float*)d_in[3];
  const float* bq = (const float*)d_in[4];
  const float* Wk = (const float*)d_in[5];
  const float* bk = (const float*)d_in[6];
  const float* Wv = (const float*)d_in[7];
  const float* bv = (const float*)d_in[8];
  const float* Wo = (const float*)d_in[9];
  const float* bo = (const float*)d_in[10];
  float* out = (float*)d_out;

  u16* ws  = (u16*)d_ws;
  u16* Xq  = ws;
  u16* Xk  = ws + ((size_t)4u<<20);
  u16* Xv  = ws + ((size_t)8u<<20);
  u16* Wqb = ws + ((size_t)12u<<20);
  u16* Wkb = ws + ((size_t)13u<<20);
  u16* Wvb = ws + ((size_t)14u<<20);
  u16* Wob = ws + ((size_t)15u<<20);
  u16* Qh  = ws + ((size_t)16u<<20);
  u16* Kh  = ws + ((size_t)20u<<20);
  u16* Vt  = ws + ((size_t)24u<<20);
  u16* comb = Xq;   // dead after gemm_qkv

  cvt_all<<<16384, 256, 0, stream>>>(q, k, v, Wq, Wk, Wv, Wo, ws);
  gemm_qkv<<<dim3(8,32,3), 256, 0, stream>>>(Xq, Xk, Xv, Wqb, Wkb, Wvb, bq, bk, bv, Qh, Kh, Vt);
  attn<<<dim3(16,32), 256, 0, stream>>>(Qh, Kh, Vt, comb);
  gemm_out<<<dim3(8,64), 256, 0, stream>>>(comb, Wob, bo, out);
}